// Round 6
// baseline (172.707 us; speedup 1.0000x reference)
//
#include <hip/hip_runtime.h>
#include <math.h>

#define B_ 32
#define N_ 512
#define F_ 1024
#define EPS 1e-6f

typedef _Float16 h8v __attribute__((ext_vector_type(8)));
typedef _Float16 h4v __attribute__((ext_vector_type(4)));
typedef float    f4v __attribute__((ext_vector_type(4)));

__device__ __forceinline__ void gl_lds16(const void* g, void* l) {
    __builtin_amdgcn_global_load_lds(
        (const __attribute__((address_space(1))) unsigned int*)g,
        (__attribute__((address_space(3))) unsigned int*)l, 16, 0, 0);
}

__device__ __forceinline__ h8v cvt8(const float4 a, const float4 c) {
    h8v h;
    h[0] = (_Float16)a.x; h[1] = (_Float16)a.y; h[2] = (_Float16)a.z; h[3] = (_Float16)a.w;
    h[4] = (_Float16)c.x; h[5] = (_Float16)c.y; h[6] = (_Float16)c.z; h[7] = (_Float16)c.w;
    return h;
}

// ---------------------------------------------------------------------------
// Kernel B: dist GEMM reading fp32 x directly. 128x128 tile, BK=64, 4 waves.
// Staging: explicit global float4 loads -> register prefetch -> cvt fp16 ->
// swizzled ds_write (no global_load_lds => no vmcnt(0) drain at the barrier;
// next step's loads fly during this step's MFMAs). Row sums/sumsq for the
// d2 epilogue are accumulated from the same staged data (slot partials ->
// LDS reduce), so no prep kernel is needed at all.
// Epilogue: d=sqrt(...), fused per-column (128-row chunk) max+sumexp ->
// pm/pl[ic=4][B][N], E = exp(d - m_chunk) fp16.
// Grid (4,4,33): z==32 blocks (16) convert W -> fp16 for kernel C.
// ---------------------------------------------------------------------------
__global__ __launch_bounds__(256) void dist_mfma(const float* __restrict__ x,
                                                 const float* __restrict__ W,
                                                 _Float16* __restrict__ Wh,
                                                 _Float16* __restrict__ Eb,
                                                 float* __restrict__ pm,
                                                 float* __restrict__ pl) {
    if (blockIdx.z == 32) {
        // W -> fp16 (16 blocks x 256 threads x 16 float4, lane-coalesced)
        int idx = (blockIdx.y * 4 + blockIdx.x) * 256 + threadIdx.x;
        const float4* src = (const float4*)W;
#pragma unroll
        for (int t = 0; t < 16; ++t) {
            float4 v = src[t * 4096 + idx];
            h4v h;
            h[0] = (_Float16)v.x; h[1] = (_Float16)v.y;
            h[2] = (_Float16)v.z; h[3] = (_Float16)v.w;
            *(h4v*)&Wh[((size_t)(t * 4096 + idx)) * 4] = h;
        }
        return;
    }

    const int b  = blockIdx.z;
    const int i0 = blockIdx.y * 128;
    const int j0 = blockIdx.x * 128;

    __shared__ __align__(16) _Float16 Ah[128 * 64];
    __shared__ __align__(16) _Float16 Bh[128 * 64];
    __shared__ float red1[2048];
    __shared__ float red2[2048];
    __shared__ float rs_s[2][128];   // side 0 = i-rows, 1 = j-rows
    __shared__ float rs_q[2][128];
    __shared__ float st_m[2][128];
    __shared__ float st_l[2][128];
    __shared__ float sm_c[128];

    const int tid  = threadIdx.x;
    const int lane = tid & 63;
    const int w    = tid >> 6;
    const int im   = (w >> 1) * 64;
    const int jn   = (w & 1) * 64;
    const int fr   = lane & 15;
    const int kq   = lane >> 4;      // 0..3
    const int q4   = kq * 4;

    // staging map: slot it (0..7): side = it>>2 (0=A,1=B),
    // row = (it&3)*32 + tid>>3, LDS chunk cs = tid&7, global chunk c8 = cs^(row&7)
    size_t gOff[8];
    int    lOff[8];
#pragma unroll
    for (int it = 0; it < 8; ++it) {
        int row = (it & 3) * 32 + (tid >> 3);
        int c8  = (tid & 7) ^ (row & 7);
        int g0  = (it < 4 ? i0 : j0) + row;
        gOff[it] = ((size_t)(b * N_ + g0)) * F_ + c8 * 8;
        lOff[it] = ((it & 3) * 256 + tid) * 8;
    }

    float4 pre[16];
#pragma unroll
    for (int s = 0; s < 8; ++s) {
        pre[2 * s]     = *(const float4*)(x + gOff[s]);
        pre[2 * s + 1] = *(const float4*)(x + gOff[s] + 4);
    }

    f4v acc[4][4] = {};
    float s1[8] = {}, s2[8] = {};

    for (int k0 = 0; k0 < F_; k0 += 64) {
        h8v hv[8];
#pragma unroll
        for (int s = 0; s < 8; ++s) {
            float4 a = pre[2 * s], c = pre[2 * s + 1];
            s1[s] += ((a.x + a.y) + (a.z + a.w)) + ((c.x + c.y) + (c.z + c.w));
            s2[s] += a.x * a.x + a.y * a.y + a.z * a.z + a.w * a.w
                   + c.x * c.x + c.y * c.y + c.z * c.z + c.w * c.w;
            hv[s] = cvt8(a, c);
        }
        __syncthreads();               // previous compute done reading LDS
#pragma unroll
        for (int s = 0; s < 4; ++s) *(h8v*)&Ah[lOff[s]] = hv[s];
#pragma unroll
        for (int s = 4; s < 8; ++s) *(h8v*)&Bh[lOff[s]] = hv[s];
        if (k0 + 64 < F_) {            // prefetch next step (drains during MFMAs)
#pragma unroll
            for (int s = 0; s < 8; ++s) {
                pre[2 * s]     = *(const float4*)(x + gOff[s] + k0 + 64);
                pre[2 * s + 1] = *(const float4*)(x + gOff[s] + k0 + 68);
            }
        }
        __syncthreads();               // LDS tiles visible

#pragma unroll
        for (int kf = 0; kf < 2; ++kf) {
            h8v a[4], bb[4];
#pragma unroll
            for (int mi = 0; mi < 4; ++mi) {
                int r = im + mi * 16 + fr;
                a[mi] = *(const h8v*)&Ah[r * 64 + (((kf << 2) | kq) ^ (r & 7)) * 8];
            }
#pragma unroll
            for (int ni = 0; ni < 4; ++ni) {
                int r = jn + ni * 16 + fr;
                bb[ni] = *(const h8v*)&Bh[r * 64 + (((kf << 2) | kq) ^ (r & 7)) * 8];
            }
#pragma unroll
            for (int mi = 0; mi < 4; ++mi)
#pragma unroll
                for (int ni = 0; ni < 4; ++ni)
                    acc[mi][ni] = __builtin_amdgcn_mfma_f32_16x16x32_f16(a[mi], bb[ni], acc[mi][ni], 0, 0, 0);
        }
    }

    // --- row-sum reduction: slot partials -> per-row s, sq ---
#pragma unroll
    for (int s = 0; s < 8; ++s) {
        int slot = (s & 3) * 256 + tid + (s >> 2) * 1024;
        red1[slot] = s1[s];
        red2[slot] = s2[s];
    }
    __syncthreads();
    {
        int side = tid >> 7, row = tid & 127;
        float a1 = 0.f, a2 = 0.f;
#pragma unroll
        for (int c = 0; c < 8; ++c) {
            a1 += red1[side * 1024 + row * 8 + c];
            a2 += red2[side * 1024 + row * 8 + c];
        }
        rs_s[side][row] = a1;
        rs_q[side][row] = a2;
    }
    __syncthreads();

    // --- epilogue 1: acc -> dist values ---
    float sqj[4], sj[4];
#pragma unroll
    for (int ni = 0; ni < 4; ++ni) {
        int jl = jn + ni * 16 + fr;
        sqj[ni] = rs_q[1][jl];
        sj[ni]  = rs_s[1][jl];
    }
#pragma unroll
    for (int mi = 0; mi < 4; ++mi)
#pragma unroll
        for (int r = 0; r < 4; ++r) {
            int il = im + mi * 16 + q4 + r;
            int i  = i0 + il;
            float sqi = rs_q[0][il];
            float si  = rs_s[0][il];
#pragma unroll
            for (int ni = 0; ni < 4; ++ni) {
                int j = j0 + jn + ni * 16 + fr;
                float d2 = sqi + sqj[ni] - 2.f * acc[mi][ni][r]
                         + 2.f * EPS * (si - sj[ni]) + (float)F_ * EPS * EPS;
                float dd = (i == j) ? 0.f : sqrtf(fmaxf(d2, 0.f));
                acc[mi][ni][r] = dd;
            }
        }

    // --- epilogue 2: per-column stats over this tile's 128 rows ---
#pragma unroll
    for (int ni = 0; ni < 4; ++ni) {
        float m_l = -1e30f;
#pragma unroll
        for (int mi = 0; mi < 4; ++mi)
#pragma unroll
            for (int r = 0; r < 4; ++r) m_l = fmaxf(m_l, acc[mi][ni][r]);
        float s_l = 0.f;
#pragma unroll
        for (int mi = 0; mi < 4; ++mi)
#pragma unroll
            for (int r = 0; r < 4; ++r) s_l += __expf(acc[mi][ni][r] - m_l);
#pragma unroll
        for (int off = 16; off < 64; off <<= 1) {
            float m_o = __shfl_xor(m_l, off);
            float s_o = __shfl_xor(s_l, off);
            float nm  = fmaxf(m_l, m_o);
            s_l = s_l * __expf(m_l - nm) + s_o * __expf(m_o - nm);
            m_l = nm;
        }
        if (lane < 16) {
            st_m[w >> 1][jn + ni * 16 + lane] = m_l;
            st_l[w >> 1][jn + ni * 16 + lane] = s_l;
        }
    }
    __syncthreads();
    if (tid < 128) {
        float m0 = st_m[0][tid], m1 = st_m[1][tid];
        float mm = fmaxf(m0, m1);
        float ss = st_l[0][tid] * __expf(m0 - mm) + st_l[1][tid] * __expf(m1 - mm);
        size_t o = ((size_t)blockIdx.y * B_ + b) * N_ + j0 + tid;
        pm[o] = mm;
        pl[o] = ss;
        sm_c[tid] = mm;
    }
    __syncthreads();

    // --- epilogue 3: E = exp(d - m_chunk) -> fp16 ---
#pragma unroll
    for (int ni = 0; ni < 4; ++ni) {
        float mc = sm_c[jn + ni * 16 + fr];
        int j = j0 + jn + ni * 16 + fr;
#pragma unroll
        for (int mi = 0; mi < 4; ++mi)
#pragma unroll
            for (int r = 0; r < 4; ++r) {
                int i = i0 + im + mi * 16 + q4 + r;
                Eb[((size_t)(b * N_ + i)) * N_ + j] = (_Float16)__expf(acc[mi][ni][r] - mc);
            }
    }
}

// ---------------------------------------------------------------------------
// Kernel C: out = (E . alpha_j) @ W^T. 128x128 tile, BK=64, swizzled LDS.
// alpha[j] = exp(pm[ic][j] - m_j)/l_j, ic = blockIdx.y (E's i-chunk), folded
// into the W-side fragments as fp16. Grid (4,4,32) = 512 blocks.
// ---------------------------------------------------------------------------
__global__ __launch_bounds__(256) void out_mfma(const _Float16* __restrict__ Eb,
                                                const _Float16* __restrict__ Wh,
                                                const float* __restrict__ pm,
                                                const float* __restrict__ pl,
                                                float* __restrict__ out) {
    const int b  = blockIdx.z;
    const int i0 = blockIdx.y * 128;
    const int k0 = blockIdx.x * 128;
    const int ic = blockIdx.y;

    __shared__ __align__(16) _Float16 As[128 * 64];
    __shared__ __align__(16) _Float16 Bs[128 * 64];
    __shared__ __align__(16) _Float16 af[N_];

    const int tid  = threadIdx.x;
    const int lane = tid & 63;
    const int w    = tid >> 6;
    const int im   = (w >> 1) * 64;
    const int kn   = (w & 1) * 64;
    const int fr   = lane & 15;
    const int kq   = lane >> 4;
    const int fk   = kq * 8;
    const int q4   = kq * 4;

    for (int j = tid; j < N_; j += 256) {
        float mx = -1e30f;
#pragma unroll
        for (int c = 0; c < 4; ++c) mx = fmaxf(mx, pm[((size_t)c * B_ + b) * N_ + j]);
        float l = 0.f;
#pragma unroll
        for (int c = 0; c < 4; ++c)
            l += pl[((size_t)c * B_ + b) * N_ + j] * __expf(pm[((size_t)c * B_ + b) * N_ + j] - mx);
        af[j] = (_Float16)(__expf(pm[((size_t)ic * B_ + b) * N_ + j] - mx) / l);
    }

    size_t aOff[4], bOff[4];
    int    lOff[4];
#pragma unroll
    for (int it = 0; it < 4; ++it) {
        int flat = it * 256 + tid;
        int row  = flat >> 3;
        int c8   = (flat & 7) ^ (row & 7);
        aOff[it] = ((size_t)(b * N_ + i0 + row)) * N_ + c8 * 8;
        bOff[it] = ((size_t)(k0 + row)) * N_ + c8 * 8;
        lOff[it] = flat * 8;
    }

    f4v acc[4][4] = {};

    for (int j0 = 0; j0 < N_; j0 += 64) {
#pragma unroll
        for (int it = 0; it < 4; ++it) {
            gl_lds16(Eb + aOff[it] + j0, &As[lOff[it]]);
            gl_lds16(Wh + bOff[it] + j0, &Bs[lOff[it]]);
        }
        __syncthreads();   // also fences the af writes on first iteration

#pragma unroll
        for (int kf = 0; kf < 2; ++kf) {
            h8v a[4], bb[4];
            h8v al = *(const h8v*)&af[j0 + kf * 32 + fk];
#pragma unroll
            for (int mi = 0; mi < 4; ++mi) {
                int r = im + mi * 16 + fr;
                a[mi] = *(const h8v*)&As[r * 64 + (((kf << 2) | kq) ^ (r & 7)) * 8];
            }
#pragma unroll
            for (int ni = 0; ni < 4; ++ni) {
                int r = kn + ni * 16 + fr;
                bb[ni] = *(const h8v*)&Bs[r * 64 + (((kf << 2) | kq) ^ (r & 7)) * 8] * al;
            }
#pragma unroll
            for (int mi = 0; mi < 4; ++mi)
#pragma unroll
                for (int ni = 0; ni < 4; ++ni)
                    acc[mi][ni] = __builtin_amdgcn_mfma_f32_16x16x32_f16(a[mi], bb[ni], acc[mi][ni], 0, 0, 0);
        }
        __syncthreads();
    }

#pragma unroll
    for (int mi = 0; mi < 4; ++mi)
#pragma unroll
        for (int r = 0; r < 4; ++r) {
            int i = i0 + im + mi * 16 + q4 + r;
#pragma unroll
            for (int ni = 0; ni < 4; ++ni) {
                int k = k0 + kn + ni * 16 + fr;
                out[((size_t)(b * N_ + i)) * N_ + k] = acc[mi][ni][r];
            }
        }
}

// ---------------------------------------------------------------------------
extern "C" void kernel_launch(void* const* d_in, const int* in_sizes, int n_in,
                              void* d_out, int out_size, void* d_ws, size_t ws_size,
                              hipStream_t stream) {
    const float* x = (const float*)d_in[0];
    const float* W = (const float*)d_in[1];
    float* out = (float*)d_out;

    const size_t NN = (size_t)B_ * N_ * N_;

    _Float16* Eb = (_Float16*)d_ws;                 // B*N*N fp16
    _Float16* Wh = Eb + NN;                         // N*N fp16
    float*    pm = (float*)(Wh + (size_t)N_ * N_);  // 4*B*N
    float*    pl = pm + (size_t)4 * B_ * N_;        // 4*B*N

    dist_mfma<<<dim3(4, 4, 33), 256, 0, stream>>>(x, W, Wh, Eb, pm, pl);
    out_mfma<<<dim3(4, 4, 32), 256, 0, stream>>>(Eb, Wh, pm, pl, out);
}

// Round 7
// 156.396 us; speedup vs baseline: 1.1043x; 1.1043x over previous
//
#include <hip/hip_runtime.h>
#include <math.h>

#define B_ 32
#define N_ 512
#define F_ 1024
#define EPS 1e-6f

typedef _Float16 h8v __attribute__((ext_vector_type(8)));
typedef _Float16 h4v __attribute__((ext_vector_type(4)));
typedef float    f4v __attribute__((ext_vector_type(4)));

__device__ __forceinline__ void gl_lds16(const void* g, void* l) {
    __builtin_amdgcn_global_load_lds(
        (const __attribute__((address_space(1))) unsigned int*)g,
        (__attribute__((address_space(3))) unsigned int*)l, 16, 0, 0);
}

// ---------------------------------------------------------------------------
// Kernel A (merged): blocks 0..4095 -> per-row sum/sumsq + x->fp16 (one wave
// per row); blocks 4096..4351 -> W->fp16.
// ---------------------------------------------------------------------------
__global__ __launch_bounds__(256) void prep_kernel(const float* __restrict__ x,
                                                   const float* __restrict__ W,
                                                   float* __restrict__ sq,
                                                   float* __restrict__ s,
                                                   _Float16* __restrict__ xh,
                                                   _Float16* __restrict__ Wh) {
    const int bid = blockIdx.x;
    if (bid < 4096) {
        int row  = bid * 4 + (threadIdx.x >> 6);
        int lane = threadIdx.x & 63;
        const float4* xr = (const float4*)(x + (size_t)row * F_);
        float a1 = 0.f, a2 = 0.f;
#pragma unroll
        for (int it = 0; it < 4; ++it) {
            float4 v = xr[lane + it * 64];
            a1 += v.x + v.y + v.z + v.w;
            a2 += v.x * v.x + v.y * v.y + v.z * v.z + v.w * v.w;
            h4v h;
            h[0] = (_Float16)v.x; h[1] = (_Float16)v.y;
            h[2] = (_Float16)v.z; h[3] = (_Float16)v.w;
            *(h4v*)&xh[(size_t)row * F_ + (size_t)(lane + it * 64) * 4] = h;
        }
#pragma unroll
        for (int off = 32; off > 0; off >>= 1) {
            a1 += __shfl_xor(a1, off);
            a2 += __shfl_xor(a2, off);
        }
        if (lane == 0) { s[row] = a1; sq[row] = a2; }
    } else {
        size_t e = ((size_t)(bid - 4096) * 256 + threadIdx.x) * 4;
        float4 v = *(const float4*)(W + e);
        h4v h;
        h[0] = (_Float16)v.x; h[1] = (_Float16)v.y;
        h[2] = (_Float16)v.z; h[3] = (_Float16)v.w;
        *(h4v*)&Wh[e] = h;
    }
}

// ---------------------------------------------------------------------------
// Kernel B: dist GEMM 128x128 tile, BK=128 (8 K-steps: half the barrier
// drains of BK=64), XOR-swizzled LDS (cg = cs ^ (row&15): frag reads are
// 2-way aliased = free), 4 waves each 64x64. Epilogue: d=sqrt(...), fused
// per-column (128-row chunk) max+sumexp -> pm/pl[ic=4][B][N],
// E = exp(d - m_chunk) fp16. Grid (4,4,32) = 512 blocks (grid-capped 2/CU;
// LDS 66 KB also allows exactly 2).
// ---------------------------------------------------------------------------
__global__ __launch_bounds__(256) void dist_mfma(const _Float16* __restrict__ xh,
                                                 const float* __restrict__ sq,
                                                 const float* __restrict__ s,
                                                 _Float16* __restrict__ Eb,
                                                 float* __restrict__ pm,
                                                 float* __restrict__ pl) {
    const int b  = blockIdx.z;
    const int i0 = blockIdx.y * 128;
    const int j0 = blockIdx.x * 128;

    __shared__ __align__(16) _Float16 Ah[128 * 128];
    __shared__ __align__(16) _Float16 Bh[128 * 128];
    __shared__ float st_m[2][128];
    __shared__ float st_l[2][128];
    __shared__ float sm_c[128];

    const int tid  = threadIdx.x;
    const int lane = tid & 63;
    const int w    = tid >> 6;
    const int im   = (w >> 1) * 64;
    const int jn   = (w & 1) * 64;
    const int fr   = lane & 15;
    const int kq   = lane >> 4;      // 0..3
    const int q4   = kq * 4;

    // staging: slot s = t*256+tid (t=0..7): row = s>>4, LDS chunk cs = s&15,
    // global chunk cg = cs ^ (row&15). 16 chunks of 8 halves per 128-row.
    size_t aOff[8], bOff[8];
    int    lOff[8];
#pragma unroll
    for (int t = 0; t < 8; ++t) {
        int ss  = t * 256 + tid;
        int row = ss >> 4;
        int cg  = (ss & 15) ^ (row & 15);
        aOff[t] = ((size_t)(b * N_ + i0 + row)) * F_ + cg * 8;
        bOff[t] = ((size_t)(b * N_ + j0 + row)) * F_ + cg * 8;
        lOff[t] = ss * 8;
    }

    f4v acc[4][4] = {};

    for (int k0 = 0; k0 < F_; k0 += 128) {
#pragma unroll
        for (int t = 0; t < 8; ++t) {
            gl_lds16(xh + aOff[t] + k0, &Ah[lOff[t]]);
            gl_lds16(xh + bOff[t] + k0, &Bh[lOff[t]]);
        }
        __syncthreads();

#pragma unroll
        for (int kf = 0; kf < 4; ++kf) {
            const int c = (kf << 2) | kq;
            h8v a[4], bb[4];
#pragma unroll
            for (int mi = 0; mi < 4; ++mi) {
                int r = im + mi * 16 + fr;
                a[mi] = *(const h8v*)&Ah[r * 128 + (c ^ (r & 15)) * 8];
            }
#pragma unroll
            for (int ni = 0; ni < 4; ++ni) {
                int r = jn + ni * 16 + fr;
                bb[ni] = *(const h8v*)&Bh[r * 128 + (c ^ (r & 15)) * 8];
            }
#pragma unroll
            for (int mi = 0; mi < 4; ++mi)
#pragma unroll
                for (int ni = 0; ni < 4; ++ni)
                    acc[mi][ni] = __builtin_amdgcn_mfma_f32_16x16x32_f16(a[mi], bb[ni], acc[mi][ni], 0, 0, 0);
        }
        __syncthreads();
    }

    // epilogue 1: acc -> dist values
    float sqj[4], sj[4];
#pragma unroll
    for (int ni = 0; ni < 4; ++ni) {
        int j = j0 + jn + ni * 16 + fr;
        sqj[ni] = sq[b * N_ + j];
        sj[ni]  = s [b * N_ + j];
    }
#pragma unroll
    for (int mi = 0; mi < 4; ++mi)
#pragma unroll
        for (int r = 0; r < 4; ++r) {
            int i = i0 + im + mi * 16 + q4 + r;
            float sqi = sq[b * N_ + i];
            float si  = s [b * N_ + i];
#pragma unroll
            for (int ni = 0; ni < 4; ++ni) {
                int j = j0 + jn + ni * 16 + fr;
                float d2 = sqi + sqj[ni] - 2.f * acc[mi][ni][r]
                         + 2.f * EPS * (si - sj[ni]) + (float)F_ * EPS * EPS;
                float dd = (i == j) ? 0.f : sqrtf(fmaxf(d2, 0.f));
                acc[mi][ni][r] = dd;
            }
        }

    // epilogue 2: per-column stats over this tile's 128 rows
#pragma unroll
    for (int ni = 0; ni < 4; ++ni) {
        float m_l = -1e30f;
#pragma unroll
        for (int mi = 0; mi < 4; ++mi)
#pragma unroll
            for (int r = 0; r < 4; ++r) m_l = fmaxf(m_l, acc[mi][ni][r]);
        float s_l = 0.f;
#pragma unroll
        for (int mi = 0; mi < 4; ++mi)
#pragma unroll
            for (int r = 0; r < 4; ++r) s_l += __expf(acc[mi][ni][r] - m_l);
#pragma unroll
        for (int off = 16; off < 64; off <<= 1) {
            float m_o = __shfl_xor(m_l, off);
            float s_o = __shfl_xor(s_l, off);
            float nm  = fmaxf(m_l, m_o);
            s_l = s_l * __expf(m_l - nm) + s_o * __expf(m_o - nm);
            m_l = nm;
        }
        if (lane < 16) {
            st_m[w >> 1][jn + ni * 16 + lane] = m_l;
            st_l[w >> 1][jn + ni * 16 + lane] = s_l;
        }
    }
    __syncthreads();
    if (tid < 128) {
        float m0 = st_m[0][tid], m1 = st_m[1][tid];
        float mm = fmaxf(m0, m1);
        float ss = st_l[0][tid] * __expf(m0 - mm) + st_l[1][tid] * __expf(m1 - mm);
        size_t o = ((size_t)blockIdx.y * B_ + b) * N_ + j0 + tid;
        pm[o] = mm;
        pl[o] = ss;
        sm_c[tid] = mm;
    }
    __syncthreads();

    // epilogue 3: E = exp(d - m_chunk) -> fp16
#pragma unroll
    for (int ni = 0; ni < 4; ++ni) {
        float mc = sm_c[jn + ni * 16 + fr];
        int j = j0 + jn + ni * 16 + fr;
#pragma unroll
        for (int mi = 0; mi < 4; ++mi)
#pragma unroll
            for (int r = 0; r < 4; ++r) {
                int i = i0 + im + mi * 16 + q4 + r;
                Eb[((size_t)(b * N_ + i)) * N_ + j] = (_Float16)__expf(acc[mi][ni][r] - mc);
            }
    }
}

// ---------------------------------------------------------------------------
// Kernel C: out = (E . alpha_j) @ W^T. 128x128 tile, BK=128 (4 K-steps),
// same swizzle. alpha[j] = exp(pm[ic][j] - m_j)/l_j, ic = blockIdx.y (E's
// i-chunk), folded into the W-side fragments as fp16. Grid (4,4,32).
// ---------------------------------------------------------------------------
__global__ __launch_bounds__(256) void out_mfma(const _Float16* __restrict__ Eb,
                                                const _Float16* __restrict__ Wh,
                                                const float* __restrict__ pm,
                                                const float* __restrict__ pl,
                                                float* __restrict__ out) {
    const int b  = blockIdx.z;
    const int i0 = blockIdx.y * 128;
    const int k0 = blockIdx.x * 128;
    const int ic = blockIdx.y;

    __shared__ __align__(16) _Float16 As[128 * 128];
    __shared__ __align__(16) _Float16 Bs[128 * 128];
    __shared__ __align__(16) _Float16 af[N_];

    const int tid  = threadIdx.x;
    const int lane = tid & 63;
    const int w    = tid >> 6;
    const int im   = (w >> 1) * 64;
    const int kn   = (w & 1) * 64;
    const int fr   = lane & 15;
    const int kq   = lane >> 4;
    const int q4   = kq * 4;

    // alpha table
    for (int j = tid; j < N_; j += 256) {
        float mx = -1e30f;
#pragma unroll
        for (int c = 0; c < 4; ++c) mx = fmaxf(mx, pm[((size_t)c * B_ + b) * N_ + j]);
        float l = 0.f;
#pragma unroll
        for (int c = 0; c < 4; ++c)
            l += pl[((size_t)c * B_ + b) * N_ + j] * __expf(pm[((size_t)c * B_ + b) * N_ + j] - mx);
        af[j] = (_Float16)(__expf(pm[((size_t)ic * B_ + b) * N_ + j] - mx) / l);
    }

    size_t aOff[8], bOff[8];
    int    lOff[8];
#pragma unroll
    for (int t = 0; t < 8; ++t) {
        int ss  = t * 256 + tid;
        int row = ss >> 4;
        int cg  = (ss & 15) ^ (row & 15);
        aOff[t] = ((size_t)(b * N_ + i0 + row)) * N_ + cg * 8;
        bOff[t] = ((size_t)(k0 + row)) * N_ + cg * 8;
        lOff[t] = ss * 8;
    }

    f4v acc[4][4] = {};

    for (int j0 = 0; j0 < N_; j0 += 128) {
#pragma unroll
        for (int t = 0; t < 8; ++t) {
            gl_lds16(Eb + aOff[t] + j0, &As[lOff[t]]);
            gl_lds16(Wh + bOff[t] + j0, &Bs[lOff[t]]);
        }
        __syncthreads();   // also fences the af writes on first iteration

#pragma unroll
        for (int kf = 0; kf < 4; ++kf) {
            const int c = (kf << 2) | kq;
            h8v a[4], bb[4];
            h8v al = *(const h8v*)&af[j0 + c * 8];
#pragma unroll
            for (int mi = 0; mi < 4; ++mi) {
                int r = im + mi * 16 + fr;
                a[mi] = *(const h8v*)&As[r * 128 + (c ^ (r & 15)) * 8];
            }
#pragma unroll
            for (int ni = 0; ni < 4; ++ni) {
                int r = kn + ni * 16 + fr;
                bb[ni] = *(const h8v*)&Bs[r * 128 + (c ^ (r & 15)) * 8] * al;
            }
#pragma unroll
            for (int mi = 0; mi < 4; ++mi)
#pragma unroll
                for (int ni = 0; ni < 4; ++ni)
                    acc[mi][ni] = __builtin_amdgcn_mfma_f32_16x16x32_f16(a[mi], bb[ni], acc[mi][ni], 0, 0, 0);
        }
        __syncthreads();
    }

#pragma unroll
    for (int mi = 0; mi < 4; ++mi)
#pragma unroll
        for (int r = 0; r < 4; ++r) {
            int i = i0 + im + mi * 16 + q4 + r;
#pragma unroll
            for (int ni = 0; ni < 4; ++ni) {
                int k = k0 + kn + ni * 16 + fr;
                out[((size_t)(b * N_ + i)) * N_ + k] = acc[mi][ni][r];
            }
        }
}

// ---------------------------------------------------------------------------
extern "C" void kernel_launch(void* const* d_in, const int* in_sizes, int n_in,
                              void* d_out, int out_size, void* d_ws, size_t ws_size,
                              hipStream_t stream) {
    const float* x = (const float*)d_in[0];
    const float* W = (const float*)d_in[1];
    float* out = (float*)d_out;

    const size_t NN = (size_t)B_ * N_ * N_;        // 8.39M elements

    _Float16* Eb = (_Float16*)d_ws;                 // B*N*N fp16
    _Float16* xh = Eb + NN;                         // B*N*F fp16
    _Float16* Wh = xh + (size_t)B_ * N_ * F_;       // N*N fp16
    float*    sq = (float*)(Wh + (size_t)N_ * N_);
    float*    s  = sq + (size_t)B_ * N_;
    float*    pm = s  + (size_t)B_ * N_;            // 4*B*N
    float*    pl = pm + (size_t)4 * B_ * N_;        // 4*B*N

    prep_kernel<<<4096 + 256, 256, 0, stream>>>(x, W, sq, s, xh, Wh);
    dist_mfma<<<dim3(N_ / 128, N_ / 128, B_), 256, 0, stream>>>(xh, sq, s, Eb, pm, pl);
    out_mfma<<<dim3(N_ / 128, N_ / 128, B_), 256, 0, stream>>>(Eb, Wh, pm, pl, out);
}